// Round 9
// baseline (263.687 us; speedup 1.0000x reference)
//
#include <hip/hip_runtime.h>

typedef unsigned short u16;
typedef unsigned int u32;
typedef unsigned long long u64;
typedef __attribute__((ext_vector_type(8))) short bf16x8;
typedef __attribute__((ext_vector_type(4))) float f32x4;

__device__ __forceinline__ float bf2f(u16 u) {
  union { u32 i; float f; } c; c.i = ((u32)u) << 16; return c.f;
}
__device__ __forceinline__ u16 f2bf(float f) {
  union { float f; u32 i; } c; c.f = f;
  u32 i = c.i;
  return (u16)((i + 0x7fffu + ((i >> 16) & 1u)) >> 16);
}
// pack two floats to two round-half-up bf16 in one u32: add, add, v_perm
__device__ __forceinline__ u32 pkbf(float a, float b) {
  union { float f; u32 i; } ca, cb; ca.f = a; cb.f = b;
  return __builtin_amdgcn_perm(cb.i + 0x8000u, ca.i + 0x8000u, 0x07060302u);
}
__device__ __forceinline__ void async16(const void* g, void* l) {
  __builtin_amdgcn_global_load_lds((const __attribute__((address_space(1))) void*)g,
                                   (__attribute__((address_space(3))) void*)l, 16, 0, 0);
}

// -------- dtype detect: f32 data -> f32 view is mid-range; bf16-pair data -> 2^~±126 ----
__global__ __launch_bounds__(256) void detect_kernel(const u32* __restrict__ X,
                                                     int* __restrict__ flag) {
  __shared__ int part[4];
  const int tid = threadIdx.x, lane = tid & 63, wave = tid >> 6;
  int votes = 0;
  for (int i = tid; i < 4096; i += 256) {
    const u32 u = X[i];
    union { u32 i; float f; } c; c.i = u;
    const float a = fabsf(c.f);
    if (u == 0u || (a > 1e-6f && a < 1e6f)) votes++;
  }
  #pragma unroll
  for (int off = 32; off >= 1; off >>= 1) votes += __shfl_xor(votes, off);
  if (lane == 0) part[wave] = votes;
  __syncthreads();
  if (tid == 0) {
    const int tot = part[0] + part[1] + part[2] + part[3];
    *flag = (tot >= 2048) ? 0 : 1;  // 0 = f32 inputs, 1 = bf16 inputs
  }
}

// --- merged prep (weight transposes z<4, bias table z==4) + rmsnorm (z>=5) ---
__global__ __launch_bounds__(256) void prep_rms_kernel(
    const void* __restrict__ W0, const void* __restrict__ W1, const void* __restrict__ W2,
    const void* __restrict__ W3, u16* __restrict__ T0, u16* __restrict__ T1,
    u16* __restrict__ T2, u16* __restrict__ T3, const void* __restrict__ rel_bias,
    float* __restrict__ Tb, const void* __restrict__ X, const void* __restrict__ LnW,
    u16* __restrict__ Normed, const int* __restrict__ flagp) {
  const int f32m = (*flagp == 0);
  const int z = blockIdx.z;
  if (z >= 5) {
    // ---------------- RMSNorm (T5 style: no mean-sub, no bias) -> bf16 ----------------
    __shared__ float part[4];
    const int tid = threadIdx.x, lane = tid & 63, wave = tid >> 6;
    const size_t row = (size_t)(z - 5) * 256 + blockIdx.y * 16 + blockIdx.x;
    const int c = tid * 4;
    float x0, x1, x2, x3, w0f, w1f, w2f, w3f;
    if (f32m) {
      const float4 xx = *(const float4*)((const float*)X + row * 1024 + c);
      x0 = xx.x; x1 = xx.y; x2 = xx.z; x3 = xx.w;
      const float4 ww = *(const float4*)((const float*)LnW + c);
      w0f = ww.x; w1f = ww.y; w2f = ww.z; w3f = ww.w;
    } else {
      const u32* px = (const u32*)((const u16*)X + row * 1024 + c);
      const u32 a0 = px[0], a1 = px[1];
      x0 = bf2f((u16)a0); x1 = bf2f((u16)(a0 >> 16));
      x2 = bf2f((u16)a1); x3 = bf2f((u16)(a1 >> 16));
      const u32* pw = (const u32*)((const u16*)LnW + c);
      const u32 b0 = pw[0], b1 = pw[1];
      w0f = bf2f((u16)b0); w1f = bf2f((u16)(b0 >> 16));
      w2f = bf2f((u16)b1); w3f = bf2f((u16)(b1 >> 16));
    }
    float ss = x0 * x0 + x1 * x1 + x2 * x2 + x3 * x3;
    #pragma unroll
    for (int off = 32; off >= 1; off >>= 1) ss += __shfl_xor(ss, off);
    if (lane == 0) part[wave] = ss;
    __syncthreads();
    const float tot = part[0] + part[1] + part[2] + part[3];
    const float scale = rsqrtf(tot * (1.0f / 1024.0f) + 1e-6f);
    const u16 o0 = f2bf(x0 * scale * w0f);
    const u16 o1 = f2bf(x1 * scale * w1f);
    const u16 o2 = f2bf(x2 * scale * w2f);
    const u16 o3 = f2bf(x3 * scale * w3f);
    u32* po = (u32*)(Normed + row * 1024 + c);
    po[0] = (u32)o0 | ((u32)o1 << 16);
    po[1] = (u32)o2 | ((u32)o3 << 16);
    return;
  }
  if (z == 4) {
    const int flat = blockIdx.y * 16 + blockIdx.x;
    const int idx = flat * 256 + threadIdx.x;
    if (idx >= 16 * 2047) return;
    const int h = idx / 2047;
    const int d = idx % 2047 - 1023;  // relative_position = mem - ctx
    const int rb = (d > 0) ? 16 : 0;
    const int rp = d < 0 ? -d : d;
    int val;
    if (rp < 8) {
      val = rp;
    } else {
      float t = (logf((float)rp * 0.125f) / 2.772588722239781f) * 8.0f;
      val = 8 + (int)t;
      if (val > 15) val = 15;
    }
    const int bi = (rb + val) * 16 + h;
    Tb[idx] = f32m ? ((const float*)rel_bias)[bi] : bf2f(((const u16*)rel_bias)[bi]);
    return;
  }
  const void* W = (z == 0) ? W0 : (z == 1) ? W1 : (z == 2) ? W2 : W3;
  u16* WT = (z == 0) ? T0 : (z == 1) ? T1 : (z == 2) ? T2 : T3;
  __shared__ u16 t[64][65];
  const int tid = threadIdx.x;
  const int tx = tid & 63, ty = tid >> 6;
  const int n0 = blockIdx.x * 64, k0 = blockIdx.y * 64;
  #pragma unroll
  for (int r = ty; r < 64; r += 4) {
    const size_t idx = (size_t)(k0 + r) * 1024 + n0 + tx;
    t[r][tx] = f32m ? f2bf(((const float*)W)[idx]) : ((const u16*)W)[idx];
  }
  __syncthreads();
  #pragma unroll
  for (int r = ty; r < 64; r += 4) WT[(size_t)(n0 + r) * 1024 + k0 + tx] = t[tx][r];
}

// ===================== pipelined 256x128 BK=64 GEMM core (out_gemm) =====================
template <int S0>
__device__ __forceinline__ void stage3(u16* lds, const u16* __restrict__ A,
                                       const u16* __restrict__ B, int m0, int n0,
                                       int kt, int w, int lane) {
  const int ko8 = ((lane & 7) ^ ((lane >> 3) & 7)) * 8;  // pre-swizzled k-octet (u16 units)
  const int rl = lane >> 3;
  #pragma unroll
  for (int s = S0; s < S0 + 3; ++s) {
    const int cw = s * 8 + w;      // wave-chunk 0..47 (1KB each)
    const int r = cw * 8 + rl;     // row 0..255 (A) / 256..383 (B)
    u16* ldst = lds + cw * 512;
    if (s < 4)
      async16(A + (size_t)(m0 + r) * 1024 + kt + ko8, ldst);
    else
      async16(B + (size_t)(n0 + r - 256) * 1024 + kt + ko8, ldst);
  }
}

template <bool SWAP>
__device__ __forceinline__ void gemm256_core(const u16* __restrict__ A,
                                             const u16* __restrict__ WT,
                                             u16 (*buf)[24576], f32x4 (&acc)[4][4],
                                             int m0, int n0, int lane, int w) {
  const int wr = w >> 1, wc = w & 1;
  const int l15 = lane & 15;
  const int ko0 = (((lane >> 4) + 0) ^ (lane & 7)) * 8;  // kk=0
  const int ko1 = (((lane >> 4) + 4) ^ (lane & 7)) * 8;  // kk=1
  const int arow = (wr * 64 + l15) * 64;
  const int brow = 16384 + (wc * 64 + l15) * 64;

  stage3<0>(buf[0], A, WT, m0, n0, 0, w, lane);
  stage3<3>(buf[0], A, WT, m0, n0, 0, w, lane);
  stage3<0>(buf[1], A, WT, m0, n0, 64, w, lane);
  stage3<3>(buf[1], A, WT, m0, n0, 64, w, lane);
  __asm__ volatile("s_waitcnt vmcnt(6)" ::: "memory");
  __builtin_amdgcn_s_barrier();
  __asm__ volatile("" ::: "memory");

  int sl = 0, sn = 2;
  #pragma unroll 1
  for (int t = 0; t < 16; ++t) {
    const u16* bc = buf[sl];
    u16* bn = buf[sn];
    const int kt2 = (t + 2) * 64;
    bf16x8 af[4][2], bfr[2][2];
    #pragma unroll
    for (int i = 0; i < 4; ++i) {
      af[i][0] = *(const bf16x8*)(bc + arow + i * 1024 + ko0);
      af[i][1] = *(const bf16x8*)(bc + arow + i * 1024 + ko1);
    }
    #pragma unroll
    for (int j = 0; j < 2; ++j) {
      bfr[j][0] = *(const bf16x8*)(bc + brow + j * 1024 + ko0);
      bfr[j][1] = *(const bf16x8*)(bc + brow + j * 1024 + ko1);
    }
    if (t < 14) stage3<0>(bn, A, WT, m0, n0, kt2, w, lane);
    __builtin_amdgcn_s_barrier();
    __asm__ volatile("s_waitcnt lgkmcnt(0)" ::: "memory");
    __builtin_amdgcn_s_setprio(1);
    #pragma unroll
    for (int i = 0; i < 4; ++i)
      #pragma unroll
      for (int j = 0; j < 2; ++j) {
        if (SWAP) {
          acc[i][j] = __builtin_amdgcn_mfma_f32_16x16x32_bf16(bfr[j][0], af[i][0], acc[i][j], 0, 0, 0);
          acc[i][j] = __builtin_amdgcn_mfma_f32_16x16x32_bf16(bfr[j][1], af[i][1], acc[i][j], 0, 0, 0);
        } else {
          acc[i][j] = __builtin_amdgcn_mfma_f32_16x16x32_bf16(af[i][0], bfr[j][0], acc[i][j], 0, 0, 0);
          acc[i][j] = __builtin_amdgcn_mfma_f32_16x16x32_bf16(af[i][1], bfr[j][1], acc[i][j], 0, 0, 0);
        }
      }
    __builtin_amdgcn_s_setprio(0);
    __builtin_amdgcn_s_barrier();
    __asm__ volatile("" ::: "memory");
    #pragma unroll
    for (int j = 0; j < 2; ++j) {
      bfr[j][0] = *(const bf16x8*)(bc + brow + (j + 2) * 1024 + ko0);
      bfr[j][1] = *(const bf16x8*)(bc + brow + (j + 2) * 1024 + ko1);
    }
    if (t < 14) stage3<3>(bn, A, WT, m0, n0, kt2, w, lane);
    __builtin_amdgcn_s_barrier();
    __asm__ volatile("s_waitcnt lgkmcnt(0)" ::: "memory");
    __builtin_amdgcn_s_setprio(1);
    #pragma unroll
    for (int i = 0; i < 4; ++i)
      #pragma unroll
      for (int j = 0; j < 2; ++j) {
        if (SWAP) {
          acc[i][j + 2] = __builtin_amdgcn_mfma_f32_16x16x32_bf16(bfr[j][0], af[i][0], acc[i][j + 2], 0, 0, 0);
          acc[i][j + 2] = __builtin_amdgcn_mfma_f32_16x16x32_bf16(bfr[j][1], af[i][1], acc[i][j + 2], 0, 0, 0);
        } else {
          acc[i][j + 2] = __builtin_amdgcn_mfma_f32_16x16x32_bf16(af[i][0], bfr[j][0], acc[i][j + 2], 0, 0, 0);
          acc[i][j + 2] = __builtin_amdgcn_mfma_f32_16x16x32_bf16(af[i][1], bfr[j][1], acc[i][j + 2], 0, 0, 0);
        }
      }
    __builtin_amdgcn_s_setprio(0);
    if (t < 14)
      __asm__ volatile("s_waitcnt vmcnt(6)" ::: "memory");
    else
      __asm__ volatile("s_waitcnt vmcnt(0)" ::: "memory");
    __builtin_amdgcn_s_barrier();
    __asm__ volatile("" ::: "memory");
    sl = (sl == 2) ? 0 : sl + 1;
    sn = (sn == 2) ? 0 : sn + 1;
  }
}

// ============ 256x128 BK=32 QKV core: 72KB LDS -> 2 blocks/CU, 1 barrier/K-tile ============
// 3 buffers x 24KB, staged 2 K-tiles ahead, counted vmcnt(3) (drain only at tail).
// Paired-row swizzle (64B rows -> 128B lines, 8 slots): slot = (octet + 4*(row&1)) ^
// (line&7); inverse-swizzled global source + swizzled ds_read (bit-exact verified in r7).
// Per K-tile per wave: 8 ds_read_b128, 3 async16, 16 MFMA, 1 lgkm, 1 vmcnt, 1 barrier.
__device__ __forceinline__ void stageK32(u16* lds, const u16* __restrict__ A,
                                         const u16* __restrict__ B, int m0, int n0,
                                         int kt, int w, int lane) {
  const int sp = (lane & 7) ^ ((lane >> 3) & 7);  // slot ^ line (involution)
  const int rl = 2 * (lane >> 3) + (sp >> 2);     // row within 16-row chunk
  const int ko = (sp & 3) * 8;                    // global k-octet (u16 units)
  #pragma unroll
  for (int s = 0; s < 3; ++s) {
    const int cw = s * 8 + w;  // chunk 0..23 (1KB = 16 rows); 0-15 = A, 16-23 = B
    u16* ldst = lds + cw * 512;
    if (s < 2)
      async16(A + (size_t)(m0 + cw * 16 + rl) * 1024 + kt + ko, ldst);
    else
      async16(B + (size_t)(n0 + (cw - 16) * 16 + rl) * 1024 + kt + ko, ldst);
  }
}

template <bool SWAP>
__device__ __forceinline__ void gemmK32_core(const u16* __restrict__ A,
                                             const u16* __restrict__ WT,
                                             u16 (*buf)[12288], f32x4 (&acc)[4][4],
                                             int m0, int n0, int lane, int w) {
  const int wr = w >> 1, wc = w & 1;
  const int l15 = lane & 15, quad = lane >> 4;
  // swizzled slot offset (u16): slot = (k-octet + 4*(row&1)) ^ (line&7)
  const int sw = ((quad + 4 * (lane & 1)) ^ ((l15 >> 1) & 7)) * 8;
  const int abase = (wr * 32 + (l15 >> 1)) * 64 + sw;          // + i*512
  const int bbase = 8192 + (wc * 32 + (l15 >> 1)) * 64 + sw;   // + j*512

  // prologue: stage tiles 0 and 1 (3 loads each per thread); tile0 resident after vmcnt(3)
  stageK32(buf[0], A, WT, m0, n0, 0, w, lane);
  stageK32(buf[1], A, WT, m0, n0, 32, w, lane);
  __asm__ volatile("s_waitcnt vmcnt(3)" ::: "memory");
  __builtin_amdgcn_s_barrier();
  __asm__ volatile("" ::: "memory");

  int sl = 0, sn = 2;
  #pragma unroll 1
  for (int t = 0; t < 32; ++t) {
    const u16* bc = buf[sl];
    bf16x8 af[4], bfr[4];
    #pragma unroll
    for (int i = 0; i < 4; ++i) af[i] = *(const bf16x8*)(bc + abase + i * 512);
    #pragma unroll
    for (int j = 0; j < 4; ++j) bfr[j] = *(const bf16x8*)(bc + bbase + j * 512);
    if (t < 30) stageK32(buf[sn], A, WT, m0, n0, (t + 2) * 32, w, lane);
    __asm__ volatile("s_waitcnt lgkmcnt(0)" ::: "memory");
    __builtin_amdgcn_s_setprio(1);
    #pragma unroll
    for (int i = 0; i < 4; ++i)
      #pragma unroll
      for (int j = 0; j < 4; ++j) {
        if (SWAP)
          acc[i][j] = __builtin_amdgcn_mfma_f32_16x16x32_bf16(bfr[j], af[i], acc[i][j], 0, 0, 0);
        else
          acc[i][j] = __builtin_amdgcn_mfma_f32_16x16x32_bf16(af[i], bfr[j], acc[i][j], 0, 0, 0);
      }
    __builtin_amdgcn_s_setprio(0);
    if (t < 30)
      __asm__ volatile("s_waitcnt vmcnt(3)" ::: "memory");  // tile t+1 resident; t+2 in flight
    else
      __asm__ volatile("s_waitcnt vmcnt(0)" ::: "memory");  // tail drain
    __builtin_amdgcn_s_barrier();
    __asm__ volatile("" ::: "memory");
    sl = (sl == 2) ? 0 : sl + 1;
    sn = (sn == 2) ? 0 : sn + 1;
  }
}

// XCD-aware swizzle: id = 8*(nb + 24*mhi) + (m&7). Grid 768; 2 blocks/CU.
__global__ __launch_bounds__(512, 4) void qkv_gemm32_kernel(
    const u16* __restrict__ A, const u16* __restrict__ WT,
    u16* __restrict__ Qo, u16* __restrict__ Ko, u16* __restrict__ VTo) {
  __shared__ __align__(16) u16 buf[3][12288];  // 3 x 24KB = 72KB
  const int tid = threadIdx.x, lane = tid & 63, w = tid >> 6;
  const int id = blockIdx.x;
  const int xcd = id & 7;
  const int t0 = id >> 3;
  const int nb = t0 % 24;
  const int mhi = t0 / 24;
  const int m0 = (mhi * 8 + xcd) * 256;
  const int n0 = nb * 128;  // in [0,3072)
  const int z = nb >> 3;    // 0=Q 1=K 2=V

  f32x4 acc[4][4];
  const f32x4 zero = {0.f, 0.f, 0.f, 0.f};
  #pragma unroll
  for (int i = 0; i < 4; ++i)
    #pragma unroll
    for (int j = 0; j < 4; ++j) acc[i][j] = zero;

  const int wr = w >> 1, wc = w & 1;
  const int cq = lane & 15, quad = lane >> 4;
  const int nbase = (n0 & 1023) + wc * 64;

  if (z == 2) {
    gemmK32_core<false>(A, WT, buf, acc, m0, n0, lane, w);
    // V^T layout: [b,h,dk,s]; lane holds 4 consecutive s for fixed (h,dk)
    #pragma unroll
    for (int i = 0; i < 4; ++i) {
      const int s = m0 + wr * 64 + i * 16 + quad * 4;
      const int b = s >> 10, s0 = s & 1023;
      #pragma unroll
      for (int j = 0; j < 4; ++j) {
        const int n = nbase + j * 16 + cq;
        const int hh = n >> 6, dk = n & 63;
        const u64 pk = (u64)f2bf(acc[i][j][0]) | ((u64)f2bf(acc[i][j][1]) << 16) |
                       ((u64)f2bf(acc[i][j][2]) << 32) | ((u64)f2bf(acc[i][j][3]) << 48);
        *(u64*)(VTo + (((size_t)(b * 16 + hh)) * 64 + dk) * 1024 + s0) = pk;
      }
    }
  } else {
    gemmK32_core<true>(A, WT, buf, acc, m0, n0, lane, w);
    u16* Out = (z == 0) ? Qo : Ko;
    // Q/K layout: [b,h,s,dk]; lane holds 4 consecutive dk for fixed s
    #pragma unroll
    for (int i = 0; i < 4; ++i) {
      const int s = m0 + wr * 64 + i * 16 + cq;
      const int b = s >> 10, ss = s & 1023;
      #pragma unroll
      for (int j = 0; j < 4; ++j) {
        const int n = nbase + j * 16 + quad * 4;
        const int hh = n >> 6, dk = n & 63;
        const u64 pk = (u64)f2bf(acc[i][j][0]) | ((u64)f2bf(acc[i][j][1]) << 16) |
                       ((u64)f2bf(acc[i][j][2]) << 32) | ((u64)f2bf(acc[i][j][3]) << 48);
        *(u64*)(Out + (((size_t)(b * 16 + hh)) * 1024 + ss) * 64 + dk) = pk;
      }
    }
  }
}

// ------- output projection on the pipelined 256x128 BK=64 core + residual epilogue -------
// M=8192 (32 panels), N=1024 (8 panels) -> 256 blocks = 1 exact round.
__global__ __launch_bounds__(512, 2) void out_gemm256_kernel(
    const u16* __restrict__ A, const u16* __restrict__ BT, const void* __restrict__ Res,
    void* __restrict__ Out, const int* __restrict__ flagp) {
  const int f32m = (*flagp == 0);
  __shared__ __align__(16) u16 buf[3][24576];  // 144KB
  const int tid = threadIdx.x, lane = tid & 63, w = tid >> 6;
  const int id = blockIdx.x;
  const int xcd = id & 7;
  const int t0 = id >> 3;
  const int nb = t0 & 7;
  const int mhi = t0 >> 3;  // 0..3
  const int m0 = (mhi * 8 + xcd) * 256;
  const int n0 = nb * 128;

  f32x4 acc[4][4];
  const f32x4 zero = {0.f, 0.f, 0.f, 0.f};
  #pragma unroll
  for (int i = 0; i < 4; ++i)
    #pragma unroll
    for (int j = 0; j < 4; ++j) acc[i][j] = zero;

  gemm256_core<true>(A, BT, buf, acc, m0, n0, lane, w);

  const int wr = w >> 1, wc = w & 1;
  const int cq = lane & 15, quad = lane >> 4;
  #pragma unroll
  for (int i = 0; i < 4; ++i) {
    const int s = m0 + wr * 64 + i * 16 + cq;
    #pragma unroll
    for (int j = 0; j < 4; ++j) {
      const int n = n0 + wc * 64 + j * 16 + quad * 4;
      const size_t idx = (size_t)s * 1024 + n;
      if (f32m) {
        const float4 rr = *(const float4*)((const float*)Res + idx);
        float4 oo;
        oo.x = rr.x + acc[i][j][0]; oo.y = rr.y + acc[i][j][1];
        oo.z = rr.z + acc[i][j][2]; oo.w = rr.w + acc[i][j][3];
        *(float4*)((float*)Out + idx) = oo;
      } else {
        const u64 rr = *(const u64*)((const u16*)Res + idx);
        const u64 pk =
            (u64)f2bf(bf2f((u16)rr) + acc[i][j][0]) |
            ((u64)f2bf(bf2f((u16)(rr >> 16)) + acc[i][j][1]) << 16) |
            ((u64)f2bf(bf2f((u16)(rr >> 32)) + acc[i][j][2]) << 32) |
            ((u64)f2bf(bf2f((u16)(rr >> 48)) + acc[i][j][3]) << 48);
        *(u64*)((u16*)Out + idx) = pk;
      }
    }
  }
}

// -------- wide flash attention: triple-buffered K/V, counted vmcnt, raw barriers --------
// Round-8 dataflow (8 waves x 32 q, cooperative K+V staging, XOR-swizzled wave-private Ps,
// LDS bias slice, S^T=K.Q^T bias C-init, out^T=V^T.P^T, setprio) with the per-tile
// vmcnt(0)+syncthreads drain replaced by: K/V staged 2 tiles ahead into 3 buffers;
// per tile wait = s_waitcnt vmcnt(2) (tile kt's 2 loads issued 2 iterations ago ->
// complete; tile kt+1's 2 stay in flight) + raw s_barrier; drain only at kt=15.
// Stage of kt+2 is issued after the barrier that retires all reads of kt-1 (its
// buffer) -> race-free. lgkmcnt(0) before the loop publishes Tbs across barrier 0.
// MFMA order identical -> bit-identical output. LDS 61KB -> 2 blocks/CU.
__global__ __launch_bounds__(512, 4) void attn_kernel(
    const u16* __restrict__ Q, const u16* __restrict__ K, const u16* __restrict__ VT,
    const float* __restrict__ Tb, u16* __restrict__ ctx) {
  __shared__ __align__(16) u16 Ks[3][4096];   // [buf][8 groups x 512] (mt,half)
  __shared__ __align__(16) u16 Vs[3][4096];   // [buf][8 groups x 512] (dt,kk)
  __shared__ __align__(16) u16 Ps[8][2048];   // wave-private [32 q][64 k] swizzled
  __shared__ __align__(16) float Tbs[1280];   // block bias slice

  const int tid = threadIdx.x, lane = tid & 63, w = tid >> 6;  // w 0..7
  const int c = lane & 15, quad = lane >> 4;
  const int id = blockIdx.x;
  const int bh = id & 127, qc = id >> 7;  // qc 0..3; same-bh blocks -> same XCD (id%8==bh%8)
  const int b = bh >> 4, h = bh & 15;
  const int q0 = qc * 256;
  const int qw = q0 + w * 32;  // wave's first q row
  const u16* Kg = K + (size_t)bh * 1024 * 64;
  const u16* Vg = VT + (size_t)bh * 64 * 1024;
  const float* Th = Tb + h * 2047;
  u16* PsW = &Ps[w][0];

  // one-time cooperative bias-slice load: Tbs[i] = Th[768 - q0 + i], i in [0,1280)
  for (int i = tid; i < 1280; i += 512) Tbs[i] = Th[768 - q0 + i];

  // hoisted Q^T B-frags: q = qw + nt*16 + c ; k-elems dk = half*32 + quad*8
  bf16x8 qf[2][2];
  {
    const u16* Qg = Q + ((size_t)bh * 1024 + qw) * 64;
    #pragma unroll
    for (int nt = 0; nt < 2; ++nt)
      #pragma unroll
      for (int half = 0; half < 2; ++half)
        qf[nt][half] = *(const bf16x8*)(Qg + (size_t)(nt * 16 + c) * 64 + half * 32 + quad * 8);
  }

  f32x4 oacc[4][2];
  const f32x4 zero = {0.f, 0.f, 0.f, 0.f};
  #pragma unroll
  for (int i = 0; i < 4; ++i)
    #pragma unroll
    for (int j = 0; j < 2; ++j) oacc[i][j] = zero;
  float rsum[2] = {0.f, 0.f};

  // cooperative staging: wave w stages K group w and V group w -> 2 async16/wave/tile
  const u16* Ksrc = Kg + (size_t)((w >> 1) * 16 + c) * 64 + (w & 1) * 32 + quad * 8;
  const u16* Vsrc = Vg + (size_t)((w >> 1) * 16 + c) * 1024 + (w & 1) * 32 + quad * 8;

  // prologue: stage tiles 0 and 1
  async16(Ksrc, &Ks[0][w * 512]);
  async16(Vsrc, &Vs[0][w * 512]);
  async16(Ksrc + (size_t)64 * 64, &Ks[1][w * 512]);
  async16(Vsrc + 64, &Vs[1][w * 512]);
  __asm__ volatile("s_waitcnt lgkmcnt(0)" ::: "memory");  // own Tbs ds_writes committed

  int sl = 0, sn = 2;
  #pragma unroll 1
  for (int kt = 0; kt < 16; ++kt) {
    const int k0 = kt * 64;
    const u16* Kc = &Ks[sl][0];
    const u16* Vc = &Vs[sl][0];
    if (kt < 15)
      __asm__ volatile("s_waitcnt vmcnt(2)" ::: "memory");  // kt resident; kt+1 in flight
    else
      __asm__ volatile("s_waitcnt vmcnt(0)" ::: "memory");  // tail drain
    __builtin_amdgcn_s_barrier();
    __asm__ volatile("" ::: "memory");
    if (kt < 14) {  // stage kt+2 into the buffer retired at the barrier above
      const int k2 = (kt + 2) * 64;
      async16(Ksrc + (size_t)k2 * 64, &Ks[sn][w * 512]);
      async16(Vsrc + k2, &Vs[sn][w * 512]);
    }
    // bias into MFMA C operand from the LDS slice:
    //   Tbs[j] = Th[j + 768 - q0]; needed Th[k - q + 1023] -> j = k0+16mt+4quad+r - c + 255 - 32w - 16nt
    f32x4 sc[4][2];
    const int jb = k0 + quad * 4 - c + 255 - 32 * w;
    #pragma unroll
    for (int mt = 0; mt < 4; ++mt)
      #pragma unroll
      for (int nt = 0; nt < 2; ++nt) {
        const float* tp = Tbs + jb + mt * 16 - nt * 16;
        sc[mt][nt][0] = tp[0]; sc[mt][nt][1] = tp[1]; sc[mt][nt][2] = tp[2]; sc[mt][nt][3] = tp[3];
      }
    // S^T = K.Q^T
    __builtin_amdgcn_s_setprio(1);
    #pragma unroll
    for (int mt = 0; mt < 4; ++mt) {
      const bf16x8 kf0 = *(const bf16x8*)(Kc + (mt * 2 + 0) * 512 + lane * 8);
      const bf16x8 kf1 = *(const bf16x8*)(Kc + (mt * 2 + 1) * 512 + lane * 8);
      #pragma unroll
      for (int nt = 0; nt < 2; ++nt) {
        sc[mt][nt] = __builtin_amdgcn_mfma_f32_16x16x32_bf16(kf0, qf[nt][0], sc[mt][nt], 0, 0, 0);
        sc[mt][nt] = __builtin_amdgcn_mfma_f32_16x16x32_bf16(kf1, qf[nt][1], sc[mt][nt], 0, 0, 0);
      }
    }
    __builtin_amdgcn_s_setprio(0);
    // exp -> rsum partial -> v_perm pack 4 consecutive k as one b64 swizzled LDS write
    #pragma unroll
    for (int mt = 0; mt < 4; ++mt)
      #pragma unroll
      for (int nt = 0; nt < 2; ++nt) {
        const float p0 = __expf(sc[mt][nt][0]), p1 = __expf(sc[mt][nt][1]);
        const float p2 = __expf(sc[mt][nt][2]), p3 = __expf(sc[mt][nt][3]);
        rsum[nt] += (p0 + p1) + (p2 + p3);
        const u32 lo = pkbf(p0, p1), hi = pkbf(p2, p3);
        const u64 pk = (u64)lo | ((u64)hi << 32);
        const int ch = (mt * 2 + (quad >> 1)) ^ (c & 7);
        *(u64*)(PsW + (nt * 16 + c) * 64 + ch * 8 + (quad & 1) * 4) = pk;
      }
    __asm__ volatile("s_waitcnt lgkmcnt(0)" ::: "memory");  // own P writes visible
    // out^T += V^T . P^T
    bf16x8 pf[2][2];
    #pragma unroll
    for (int nt = 0; nt < 2; ++nt)
      #pragma unroll
      for (int kk = 0; kk < 2; ++kk) {
        const int ch = (kk * 4 + quad) ^ (c & 7);
        pf[nt][kk] = *(const bf16x8*)(PsW + (nt * 16 + c) * 64 + ch * 8);
      }
    __builtin_amdgcn_s_setprio(1);
    #pragma unroll
    for (int dt = 0; dt < 4; ++dt) {
      const bf16x8 vf0 = *(const bf16x8*)(Vc + (dt * 2 + 0) * 512 + lane * 8);
      const bf16x8 vf1 = *(const bf16x8*)(Vc + (dt * 2 + 1) * 512 + lane * 8);
      #pragma unroll
      for (int nt = 0; nt < 2; ++nt) {
        oacc[dt][nt] = __builtin_amdgcn_mfma_f32_16x16x32_bf16(vf0, pf[nt][0], oacc[dt][nt], 0, 0, 0);
        oacc[dt][nt] = __builtin_amdgcn_mfma_f32_16x16x32_bf16(vf1, pf[nt][1], oacc[dt][nt], 0, 0, 0);
      }
    }
    __builtin_amdgcn_s_setprio(0);
    sl = (sl == 2) ? 0 : sl + 1;
    sn = (sn == 2) ? 0 : sn + 1;
  }

  // fold quads: lanes (c, c+16, c+32, c+48) hold disjoint k-partitions of q-row c
  #pragma unroll
  for (int nt = 0; nt < 2; ++nt) {
    rsum[nt] += __shfl_xor(rsum[nt], 16);
    rsum[nt] += __shfl_xor(rsum[nt], 32);
  }

  #pragma unroll
  for (int nt = 0; nt < 2; ++nt) {
    const float inv = 1.0f / rsum[nt];
    const int q = qw + nt * 16 + c;
    #pragma unroll
    for (int dt = 0; dt < 4; ++dt) {
      const u64 pk = (u64)f2bf(oacc[dt][nt][0] * inv) | ((u64)f2bf(oacc[dt][nt][1] * inv) << 16) |
                     ((u64)f2bf(oacc[dt][nt][2] * inv) << 32) | ((u64)f2bf(oacc[dt][nt][3] * inv) << 48);
      // ctx layout: [b, s, h, dk]; lane holds 4 consecutive dk = dt*16 + quad*4 + r
      *(u64*)(ctx + (((size_t)b * 1024 + q) * 16 + h) * 64 + dt * 16 + quad * 4) = pk;
    }
  }
}

extern "C" void kernel_launch(void* const* d_in, const int* in_sizes, int n_in,
                              void* d_out, int out_size, void* d_ws, size_t ws_size,
                              hipStream_t stream) {
  const void* hidden = d_in[0];
  const void* lnw = d_in[1];
  const void* wq = d_in[2];
  const void* wk = d_in[3];
  const void* wv = d_in[4];
  const void* wo = d_in[5];
  const void* relb = d_in[6];
  char* ws = (char*)d_ws;

  u16* normed = (u16*)(ws);                        // 16 MB; reused as ctx after QKV
  u16* Qb = (u16*)(ws + ((size_t)16 << 20));       // 16 MB
  u16* Kb = (u16*)(ws + ((size_t)32 << 20));       // 16 MB
  u16* VTb = (u16*)(ws + ((size_t)48 << 20));      // 16 MB
  u16* wtq = (u16*)(ws + ((size_t)64 << 20));      // [3072][1024] fused B: wtq|wtk|wtv
  u16* wtk = (u16*)(ws + ((size_t)64 << 20) + (2 << 20));
  u16* wtv = (u16*)(ws + ((size_t)64 << 20) + (4 << 20));
  u16* wto = (u16*)(ws + ((size_t)64 << 20) + (6 << 20));
  float* Tb = (float*)(ws + ((size_t)64 << 20) + (8 << 20));  // 131 KB
  int* flag = (int*)(ws + ((size_t)64 << 20) + (9 << 20));

  dim3 b256(256);
  detect_kernel<<<dim3(1), b256, 0, stream>>>((const u32*)hidden, flag);
  prep_rms_kernel<<<dim3(16, 16, 37), b256, 0, stream>>>(wq, wk, wv, wo, wtq, wtk, wtv,
                                                         wto, relb, Tb, hidden, lnw,
                                                         normed, flag);
  qkv_gemm32_kernel<<<dim3(768), dim3(512), 0, stream>>>(normed, wtq, Qb, Kb, VTb);
  attn_kernel<<<dim3(512), dim3(512), 0, stream>>>(Qb, Kb, VTb, Tb, normed);
  out_gemm256_kernel<<<dim3(256), dim3(512), 0, stream>>>(normed, wto, hidden, d_out, flag);
}

// Round 10
// 244.677 us; speedup vs baseline: 1.0777x; 1.0777x over previous
//
#include <hip/hip_runtime.h>

typedef unsigned short u16;
typedef unsigned int u32;
typedef unsigned long long u64;
typedef __attribute__((ext_vector_type(8))) short bf16x8;
typedef __attribute__((ext_vector_type(4))) float f32x4;

__device__ __forceinline__ float bf2f(u16 u) {
  union { u32 i; float f; } c; c.i = ((u32)u) << 16; return c.f;
}
__device__ __forceinline__ u16 f2bf(float f) {
  union { float f; u32 i; } c; c.f = f;
  u32 i = c.i;
  return (u16)((i + 0x7fffu + ((i >> 16) & 1u)) >> 16);
}
// pack two floats to two round-half-up bf16 in one u32: add, add, v_perm
__device__ __forceinline__ u32 pkbf(float a, float b) {
  union { float f; u32 i; } ca, cb; ca.f = a; cb.f = b;
  return __builtin_amdgcn_perm(cb.i + 0x8000u, ca.i + 0x8000u, 0x07060302u);
}
__device__ __forceinline__ void async16(const void* g, void* l) {
  __builtin_amdgcn_global_load_lds((const __attribute__((address_space(1))) void*)g,
                                   (__attribute__((address_space(3))) void*)l, 16, 0, 0);
}

// -------- dtype detect: f32 data -> f32 view is mid-range; bf16-pair data -> 2^~±126 ----
__global__ __launch_bounds__(256) void detect_kernel(const u32* __restrict__ X,
                                                     int* __restrict__ flag) {
  __shared__ int part[4];
  const int tid = threadIdx.x, lane = tid & 63, wave = tid >> 6;
  int votes = 0;
  for (int i = tid; i < 4096; i += 256) {
    const u32 u = X[i];
    union { u32 i; float f; } c; c.i = u;
    const float a = fabsf(c.f);
    if (u == 0u || (a > 1e-6f && a < 1e6f)) votes++;
  }
  #pragma unroll
  for (int off = 32; off >= 1; off >>= 1) votes += __shfl_xor(votes, off);
  if (lane == 0) part[wave] = votes;
  __syncthreads();
  if (tid == 0) {
    const int tot = part[0] + part[1] + part[2] + part[3];
    *flag = (tot >= 2048) ? 0 : 1;  // 0 = f32 inputs, 1 = bf16 inputs
  }
}

// --- merged prep (weight transposes z<4, bias table z==4) + rmsnorm (z>=5) ---
__global__ __launch_bounds__(256) void prep_rms_kernel(
    const void* __restrict__ W0, const void* __restrict__ W1, const void* __restrict__ W2,
    const void* __restrict__ W3, u16* __restrict__ T0, u16* __restrict__ T1,
    u16* __restrict__ T2, u16* __restrict__ T3, const void* __restrict__ rel_bias,
    float* __restrict__ Tb, const void* __restrict__ X, const void* __restrict__ LnW,
    u16* __restrict__ Normed, const int* __restrict__ flagp) {
  const int f32m = (*flagp == 0);
  const int z = blockIdx.z;
  if (z >= 5) {
    // ---------------- RMSNorm (T5 style: no mean-sub, no bias) -> bf16 ----------------
    __shared__ float part[4];
    const int tid = threadIdx.x, lane = tid & 63, wave = tid >> 6;
    const size_t row = (size_t)(z - 5) * 256 + blockIdx.y * 16 + blockIdx.x;
    const int c = tid * 4;
    float x0, x1, x2, x3, w0f, w1f, w2f, w3f;
    if (f32m) {
      const float4 xx = *(const float4*)((const float*)X + row * 1024 + c);
      x0 = xx.x; x1 = xx.y; x2 = xx.z; x3 = xx.w;
      const float4 ww = *(const float4*)((const float*)LnW + c);
      w0f = ww.x; w1f = ww.y; w2f = ww.z; w3f = ww.w;
    } else {
      const u32* px = (const u32*)((const u16*)X + row * 1024 + c);
      const u32 a0 = px[0], a1 = px[1];
      x0 = bf2f((u16)a0); x1 = bf2f((u16)(a0 >> 16));
      x2 = bf2f((u16)a1); x3 = bf2f((u16)(a1 >> 16));
      const u32* pw = (const u32*)((const u16*)LnW + c);
      const u32 b0 = pw[0], b1 = pw[1];
      w0f = bf2f((u16)b0); w1f = bf2f((u16)(b0 >> 16));
      w2f = bf2f((u16)b1); w3f = bf2f((u16)(b1 >> 16));
    }
    float ss = x0 * x0 + x1 * x1 + x2 * x2 + x3 * x3;
    #pragma unroll
    for (int off = 32; off >= 1; off >>= 1) ss += __shfl_xor(ss, off);
    if (lane == 0) part[wave] = ss;
    __syncthreads();
    const float tot = part[0] + part[1] + part[2] + part[3];
    const float scale = rsqrtf(tot * (1.0f / 1024.0f) + 1e-6f);
    const u16 o0 = f2bf(x0 * scale * w0f);
    const u16 o1 = f2bf(x1 * scale * w1f);
    const u16 o2 = f2bf(x2 * scale * w2f);
    const u16 o3 = f2bf(x3 * scale * w3f);
    u32* po = (u32*)(Normed + row * 1024 + c);
    po[0] = (u32)o0 | ((u32)o1 << 16);
    po[1] = (u32)o2 | ((u32)o3 << 16);
    return;
  }
  if (z == 4) {
    const int flat = blockIdx.y * 16 + blockIdx.x;
    const int idx = flat * 256 + threadIdx.x;
    if (idx >= 16 * 2047) return;
    const int h = idx / 2047;
    const int d = idx % 2047 - 1023;  // relative_position = mem - ctx
    const int rb = (d > 0) ? 16 : 0;
    const int rp = d < 0 ? -d : d;
    int val;
    if (rp < 8) {
      val = rp;
    } else {
      float t = (logf((float)rp * 0.125f) / 2.772588722239781f) * 8.0f;
      val = 8 + (int)t;
      if (val > 15) val = 15;
    }
    const int bi = (rb + val) * 16 + h;
    Tb[idx] = f32m ? ((const float*)rel_bias)[bi] : bf2f(((const u16*)rel_bias)[bi]);
    return;
  }
  const void* W = (z == 0) ? W0 : (z == 1) ? W1 : (z == 2) ? W2 : W3;
  u16* WT = (z == 0) ? T0 : (z == 1) ? T1 : (z == 2) ? T2 : T3;
  __shared__ u16 t[64][65];
  const int tid = threadIdx.x;
  const int tx = tid & 63, ty = tid >> 6;
  const int n0 = blockIdx.x * 64, k0 = blockIdx.y * 64;
  #pragma unroll
  for (int r = ty; r < 64; r += 4) {
    const size_t idx = (size_t)(k0 + r) * 1024 + n0 + tx;
    t[r][tx] = f32m ? f2bf(((const float*)W)[idx]) : ((const u16*)W)[idx];
  }
  __syncthreads();
  #pragma unroll
  for (int r = ty; r < 64; r += 4) WT[(size_t)(n0 + r) * 1024 + k0 + tx] = t[tx][r];
}

// ===================== pipelined 256x128 BK=64 GEMM core (out_gemm) =====================
template <int S0>
__device__ __forceinline__ void stage3(u16* lds, const u16* __restrict__ A,
                                       const u16* __restrict__ B, int m0, int n0,
                                       int kt, int w, int lane) {
  const int ko8 = ((lane & 7) ^ ((lane >> 3) & 7)) * 8;  // pre-swizzled k-octet (u16 units)
  const int rl = lane >> 3;
  #pragma unroll
  for (int s = S0; s < S0 + 3; ++s) {
    const int cw = s * 8 + w;      // wave-chunk 0..47 (1KB each)
    const int r = cw * 8 + rl;     // row 0..255 (A) / 256..383 (B)
    u16* ldst = lds + cw * 512;
    if (s < 4)
      async16(A + (size_t)(m0 + r) * 1024 + kt + ko8, ldst);
    else
      async16(B + (size_t)(n0 + r - 256) * 1024 + kt + ko8, ldst);
  }
}

template <bool SWAP>
__device__ __forceinline__ void gemm256_core(const u16* __restrict__ A,
                                             const u16* __restrict__ WT,
                                             u16 (*buf)[24576], f32x4 (&acc)[4][4],
                                             int m0, int n0, int lane, int w) {
  const int wr = w >> 1, wc = w & 1;
  const int l15 = lane & 15;
  const int ko0 = (((lane >> 4) + 0) ^ (lane & 7)) * 8;  // kk=0
  const int ko1 = (((lane >> 4) + 4) ^ (lane & 7)) * 8;  // kk=1
  const int arow = (wr * 64 + l15) * 64;
  const int brow = 16384 + (wc * 64 + l15) * 64;

  stage3<0>(buf[0], A, WT, m0, n0, 0, w, lane);
  stage3<3>(buf[0], A, WT, m0, n0, 0, w, lane);
  stage3<0>(buf[1], A, WT, m0, n0, 64, w, lane);
  stage3<3>(buf[1], A, WT, m0, n0, 64, w, lane);
  __asm__ volatile("s_waitcnt vmcnt(6)" ::: "memory");
  __builtin_amdgcn_s_barrier();
  __asm__ volatile("" ::: "memory");

  int sl = 0, sn = 2;
  #pragma unroll 1
  for (int t = 0; t < 16; ++t) {
    const u16* bc = buf[sl];
    u16* bn = buf[sn];
    const int kt2 = (t + 2) * 64;
    bf16x8 af[4][2], bfr[2][2];
    #pragma unroll
    for (int i = 0; i < 4; ++i) {
      af[i][0] = *(const bf16x8*)(bc + arow + i * 1024 + ko0);
      af[i][1] = *(const bf16x8*)(bc + arow + i * 1024 + ko1);
    }
    #pragma unroll
    for (int j = 0; j < 2; ++j) {
      bfr[j][0] = *(const bf16x8*)(bc + brow + j * 1024 + ko0);
      bfr[j][1] = *(const bf16x8*)(bc + brow + j * 1024 + ko1);
    }
    if (t < 14) stage3<0>(bn, A, WT, m0, n0, kt2, w, lane);
    __builtin_amdgcn_s_barrier();
    __asm__ volatile("s_waitcnt lgkmcnt(0)" ::: "memory");
    __builtin_amdgcn_s_setprio(1);
    #pragma unroll
    for (int i = 0; i < 4; ++i)
      #pragma unroll
      for (int j = 0; j < 2; ++j) {
        if (SWAP) {
          acc[i][j] = __builtin_amdgcn_mfma_f32_16x16x32_bf16(bfr[j][0], af[i][0], acc[i][j], 0, 0, 0);
          acc[i][j] = __builtin_amdgcn_mfma_f32_16x16x32_bf16(bfr[j][1], af[i][1], acc[i][j], 0, 0, 0);
        } else {
          acc[i][j] = __builtin_amdgcn_mfma_f32_16x16x32_bf16(af[i][0], bfr[j][0], acc[i][j], 0, 0, 0);
          acc[i][j] = __builtin_amdgcn_mfma_f32_16x16x32_bf16(af[i][1], bfr[j][1], acc[i][j], 0, 0, 0);
        }
      }
    __builtin_amdgcn_s_setprio(0);
    __builtin_amdgcn_s_barrier();
    __asm__ volatile("" ::: "memory");
    #pragma unroll
    for (int j = 0; j < 2; ++j) {
      bfr[j][0] = *(const bf16x8*)(bc + brow + (j + 2) * 1024 + ko0);
      bfr[j][1] = *(const bf16x8*)(bc + brow + (j + 2) * 1024 + ko1);
    }
    if (t < 14) stage3<3>(bn, A, WT, m0, n0, kt2, w, lane);
    __builtin_amdgcn_s_barrier();
    __asm__ volatile("s_waitcnt lgkmcnt(0)" ::: "memory");
    __builtin_amdgcn_s_setprio(1);
    #pragma unroll
    for (int i = 0; i < 4; ++i)
      #pragma unroll
      for (int j = 0; j < 2; ++j) {
        if (SWAP) {
          acc[i][j + 2] = __builtin_amdgcn_mfma_f32_16x16x32_bf16(bfr[j][0], af[i][0], acc[i][j + 2], 0, 0, 0);
          acc[i][j + 2] = __builtin_amdgcn_mfma_f32_16x16x32_bf16(bfr[j][1], af[i][1], acc[i][j + 2], 0, 0, 0);
        } else {
          acc[i][j + 2] = __builtin_amdgcn_mfma_f32_16x16x32_bf16(af[i][0], bfr[j][0], acc[i][j + 2], 0, 0, 0);
          acc[i][j + 2] = __builtin_amdgcn_mfma_f32_16x16x32_bf16(af[i][1], bfr[j][1], acc[i][j + 2], 0, 0, 0);
        }
      }
    __builtin_amdgcn_s_setprio(0);
    if (t < 14)
      __asm__ volatile("s_waitcnt vmcnt(6)" ::: "memory");
    else
      __asm__ volatile("s_waitcnt vmcnt(0)" ::: "memory");
    __builtin_amdgcn_s_barrier();
    __asm__ volatile("" ::: "memory");
    sl = (sl == 2) ? 0 : sl + 1;
    sn = (sn == 2) ? 0 : sn + 1;
  }
}

// ============ 256x128 BK=32 QKV core: 72KB LDS -> 2 blocks/CU, 1 barrier/K-tile ============
// (kept from round 9: ~67us vs round-8's 71.4) 3 buffers x 24KB, staged 2 K-tiles ahead,
// counted vmcnt(3). Paired-row involution swizzle (64B rows -> 128B lines).
__device__ __forceinline__ void stageK32(u16* lds, const u16* __restrict__ A,
                                         const u16* __restrict__ B, int m0, int n0,
                                         int kt, int w, int lane) {
  const int sp = (lane & 7) ^ ((lane >> 3) & 7);  // slot ^ line (involution)
  const int rl = 2 * (lane >> 3) + (sp >> 2);     // row within 16-row chunk
  const int ko = (sp & 3) * 8;                    // global k-octet (u16 units)
  #pragma unroll
  for (int s = 0; s < 3; ++s) {
    const int cw = s * 8 + w;  // chunk 0..23 (1KB = 16 rows); 0-15 = A, 16-23 = B
    u16* ldst = lds + cw * 512;
    if (s < 2)
      async16(A + (size_t)(m0 + cw * 16 + rl) * 1024 + kt + ko, ldst);
    else
      async16(B + (size_t)(n0 + (cw - 16) * 16 + rl) * 1024 + kt + ko, ldst);
  }
}

template <bool SWAP>
__device__ __forceinline__ void gemmK32_core(const u16* __restrict__ A,
                                             const u16* __restrict__ WT,
                                             u16 (*buf)[12288], f32x4 (&acc)[4][4],
                                             int m0, int n0, int lane, int w) {
  const int wr = w >> 1, wc = w & 1;
  const int l15 = lane & 15, quad = lane >> 4;
  // swizzled slot offset (u16): slot = (k-octet + 4*(row&1)) ^ (line&7)
  const int sw = ((quad + 4 * (lane & 1)) ^ ((l15 >> 1) & 7)) * 8;
  const int abase = (wr * 32 + (l15 >> 1)) * 64 + sw;          // + i*512
  const int bbase = 8192 + (wc * 32 + (l15 >> 1)) * 64 + sw;   // + j*512

  stageK32(buf[0], A, WT, m0, n0, 0, w, lane);
  stageK32(buf[1], A, WT, m0, n0, 32, w, lane);
  __asm__ volatile("s_waitcnt vmcnt(3)" ::: "memory");
  __builtin_amdgcn_s_barrier();
  __asm__ volatile("" ::: "memory");

  int sl = 0, sn = 2;
  #pragma unroll 1
  for (int t = 0; t < 32; ++t) {
    const u16* bc = buf[sl];
    bf16x8 af[4], bfr[4];
    #pragma unroll
    for (int i = 0; i < 4; ++i) af[i] = *(const bf16x8*)(bc + abase + i * 512);
    #pragma unroll
    for (int j = 0; j < 4; ++j) bfr[j] = *(const bf16x8*)(bc + bbase + j * 512);
    if (t < 30) stageK32(buf[sn], A, WT, m0, n0, (t + 2) * 32, w, lane);
    __asm__ volatile("s_waitcnt lgkmcnt(0)" ::: "memory");
    __builtin_amdgcn_s_setprio(1);
    #pragma unroll
    for (int i = 0; i < 4; ++i)
      #pragma unroll
      for (int j = 0; j < 4; ++j) {
        if (SWAP)
          acc[i][j] = __builtin_amdgcn_mfma_f32_16x16x32_bf16(bfr[j], af[i], acc[i][j], 0, 0, 0);
        else
          acc[i][j] = __builtin_amdgcn_mfma_f32_16x16x32_bf16(af[i], bfr[j], acc[i][j], 0, 0, 0);
      }
    __builtin_amdgcn_s_setprio(0);
    if (t < 30)
      __asm__ volatile("s_waitcnt vmcnt(3)" ::: "memory");  // tile t+1 resident; t+2 in flight
    else
      __asm__ volatile("s_waitcnt vmcnt(0)" ::: "memory");  // tail drain
    __builtin_amdgcn_s_barrier();
    __asm__ volatile("" ::: "memory");
    sl = (sl == 2) ? 0 : sl + 1;
    sn = (sn == 2) ? 0 : sn + 1;
  }
}

// XCD-aware swizzle: id = 8*(nb + 24*mhi) + (m&7). Grid 768; 2 blocks/CU.
__global__ __launch_bounds__(512, 4) void qkv_gemm32_kernel(
    const u16* __restrict__ A, const u16* __restrict__ WT,
    u16* __restrict__ Qo, u16* __restrict__ Ko, u16* __restrict__ VTo) {
  __shared__ __align__(16) u16 buf[3][12288];  // 3 x 24KB = 72KB
  const int tid = threadIdx.x, lane = tid & 63, w = tid >> 6;
  const int id = blockIdx.x;
  const int xcd = id & 7;
  const int t0 = id >> 3;
  const int nb = t0 % 24;
  const int mhi = t0 / 24;
  const int m0 = (mhi * 8 + xcd) * 256;
  const int n0 = nb * 128;  // in [0,3072)
  const int z = nb >> 3;    // 0=Q 1=K 2=V

  f32x4 acc[4][4];
  const f32x4 zero = {0.f, 0.f, 0.f, 0.f};
  #pragma unroll
  for (int i = 0; i < 4; ++i)
    #pragma unroll
    for (int j = 0; j < 4; ++j) acc[i][j] = zero;

  const int wr = w >> 1, wc = w & 1;
  const int cq = lane & 15, quad = lane >> 4;
  const int nbase = (n0 & 1023) + wc * 64;

  if (z == 2) {
    gemmK32_core<false>(A, WT, buf, acc, m0, n0, lane, w);
    // V^T layout: [b,h,dk,s]; lane holds 4 consecutive s for fixed (h,dk)
    #pragma unroll
    for (int i = 0; i < 4; ++i) {
      const int s = m0 + wr * 64 + i * 16 + quad * 4;
      const int b = s >> 10, s0 = s & 1023;
      #pragma unroll
      for (int j = 0; j < 4; ++j) {
        const int n = nbase + j * 16 + cq;
        const int hh = n >> 6, dk = n & 63;
        const u64 pk = (u64)f2bf(acc[i][j][0]) | ((u64)f2bf(acc[i][j][1]) << 16) |
                       ((u64)f2bf(acc[i][j][2]) << 32) | ((u64)f2bf(acc[i][j][3]) << 48);
        *(u64*)(VTo + (((size_t)(b * 16 + hh)) * 64 + dk) * 1024 + s0) = pk;
      }
    }
  } else {
    gemmK32_core<true>(A, WT, buf, acc, m0, n0, lane, w);
    u16* Out = (z == 0) ? Qo : Ko;
    // Q/K layout: [b,h,s,dk]; lane holds 4 consecutive dk for fixed s
    #pragma unroll
    for (int i = 0; i < 4; ++i) {
      const int s = m0 + wr * 64 + i * 16 + cq;
      const int b = s >> 10, ss = s & 1023;
      #pragma unroll
      for (int j = 0; j < 4; ++j) {
        const int n = nbase + j * 16 + quad * 4;
        const int hh = n >> 6, dk = n & 63;
        const u64 pk = (u64)f2bf(acc[i][j][0]) | ((u64)f2bf(acc[i][j][1]) << 16) |
                       ((u64)f2bf(acc[i][j][2]) << 32) | ((u64)f2bf(acc[i][j][3]) << 48);
        *(u64*)(Out + (((size_t)(b * 16 + hh)) * 1024 + ss) * 64 + dk) = pk;
      }
    }
  }
}

// ------- output projection on the pipelined 256x128 BK=64 core + residual epilogue -------
// M=8192 (32 panels), N=1024 (8 panels) -> 256 blocks = 1 exact round.
__global__ __launch_bounds__(512, 2) void out_gemm256_kernel(
    const u16* __restrict__ A, const u16* __restrict__ BT, const void* __restrict__ Res,
    void* __restrict__ Out, const int* __restrict__ flagp) {
  const int f32m = (*flagp == 0);
  __shared__ __align__(16) u16 buf[3][24576];  // 144KB
  const int tid = threadIdx.x, lane = tid & 63, w = tid >> 6;
  const int id = blockIdx.x;
  const int xcd = id & 7;
  const int t0 = id >> 3;
  const int nb = t0 & 7;
  const int mhi = t0 >> 3;  // 0..3
  const int m0 = (mhi * 8 + xcd) * 256;
  const int n0 = nb * 128;

  f32x4 acc[4][4];
  const f32x4 zero = {0.f, 0.f, 0.f, 0.f};
  #pragma unroll
  for (int i = 0; i < 4; ++i)
    #pragma unroll
    for (int j = 0; j < 4; ++j) acc[i][j] = zero;

  gemm256_core<true>(A, BT, buf, acc, m0, n0, lane, w);

  const int wr = w >> 1, wc = w & 1;
  const int cq = lane & 15, quad = lane >> 4;
  #pragma unroll
  for (int i = 0; i < 4; ++i) {
    const int s = m0 + wr * 64 + i * 16 + cq;
    #pragma unroll
    for (int j = 0; j < 4; ++j) {
      const int n = n0 + wc * 64 + j * 16 + quad * 4;
      const size_t idx = (size_t)s * 1024 + n;
      if (f32m) {
        const float4 rr = *(const float4*)((const float*)Res + idx);
        float4 oo;
        oo.x = rr.x + acc[i][j][0]; oo.y = rr.y + acc[i][j][1];
        oo.z = rr.z + acc[i][j][2]; oo.w = rr.w + acc[i][j][3];
        *(float4*)((float*)Out + idx) = oo;
      } else {
        const u64 rr = *(const u64*)((const u16*)Res + idx);
        const u64 pk =
            (u64)f2bf(bf2f((u16)rr) + acc[i][j][0]) |
            ((u64)f2bf(bf2f((u16)(rr >> 16)) + acc[i][j][1]) << 16) |
            ((u64)f2bf(bf2f((u16)(rr >> 32)) + acc[i][j][2]) << 32) |
            ((u64)f2bf(bf2f((u16)(rr >> 48)) + acc[i][j][3]) << 48);
        *(u64*)((u16*)Out + idx) = pk;
      }
    }
  }
}

// -------- wide flash attention: counted vmcnt, K 3-buf + V 2-buf = 77KB (2 blocks/CU) --------
// Round-9 counted-vmcnt structure with the LDS regression fixed: V is double-buffered and
// staged 1 tile ahead, K triple-buffered 2 ahead. Per-wave issue order each iter is V first
// then K, so the FIFO at the top of iter kt is [V(kt), K(kt+1)]: s_waitcnt vmcnt(1)
// completes V(kt) (and older K(kt)) while K(kt+1) stays in flight -> no mid-loop drain.
// V buf (kt+1)&1 was last read in iter kt-1, retired by the top barrier -> race-free.
// MFMA order identical to round 8 -> bit-identical output.
__global__ __launch_bounds__(512, 4) void attn_kernel(
    const u16* __restrict__ Q, const u16* __restrict__ K, const u16* __restrict__ VT,
    const float* __restrict__ Tb, u16* __restrict__ ctx) {
  __shared__ __align__(16) u16 Ks[3][4096];   // [buf][8 groups x 512] (mt,half)
  __shared__ __align__(16) u16 Vs[2][4096];   // [buf][8 groups x 512] (dt,kk)
  __shared__ __align__(16) u16 Ps[8][2048];   // wave-private [32 q][64 k] swizzled
  __shared__ __align__(16) float Tbs[1280];   // block bias slice

  const int tid = threadIdx.x, lane = tid & 63, w = tid >> 6;  // w 0..7
  const int c = lane & 15, quad = lane >> 4;
  const int id = blockIdx.x;
  const int bh = id & 127, qc = id >> 7;  // qc 0..3; same-bh blocks -> same XCD (id%8==bh%8)
  const int b = bh >> 4, h = bh & 15;
  const int q0 = qc * 256;
  const int qw = q0 + w * 32;  // wave's first q row
  const u16* Kg = K + (size_t)bh * 1024 * 64;
  const u16* Vg = VT + (size_t)bh * 64 * 1024;
  const float* Th = Tb + h * 2047;
  u16* PsW = &Ps[w][0];

  // one-time cooperative bias-slice load: Tbs[i] = Th[768 - q0 + i], i in [0,1280)
  for (int i = tid; i < 1280; i += 512) Tbs[i] = Th[768 - q0 + i];

  // hoisted Q^T B-frags: q = qw + nt*16 + c ; k-elems dk = half*32 + quad*8
  bf16x8 qf[2][2];
  {
    const u16* Qg = Q + ((size_t)bh * 1024 + qw) * 64;
    #pragma unroll
    for (int nt = 0; nt < 2; ++nt)
      #pragma unroll
      for (int half = 0; half < 2; ++half)
        qf[nt][half] = *(const bf16x8*)(Qg + (size_t)(nt * 16 + c) * 64 + half * 32 + quad * 8);
  }

  f32x4 oacc[4][2];
  const f32x4 zero = {0.f, 0.f, 0.f, 0.f};
  #pragma unroll
  for (int i = 0; i < 4; ++i)
    #pragma unroll
    for (int j = 0; j < 2; ++j) oacc[i][j] = zero;
  float rsum[2] = {0.f, 0.f};

  // cooperative staging: wave w stages K group w and V group w
  const u16* Ksrc = Kg + (size_t)((w >> 1) * 16 + c) * 64 + (w & 1) * 32 + quad * 8;
  const u16* Vsrc = Vg + (size_t)((w >> 1) * 16 + c) * 1024 + (w & 1) * 32 + quad * 8;

  // prologue FIFO: V(0), K(0), K(1) -> vmcnt(1) at iter-0 top leaves K(1) in flight
  async16(Vsrc, &Vs[0][w * 512]);
  async16(Ksrc, &Ks[0][w * 512]);
  async16(Ksrc + (size_t)64 * 64, &Ks[1][w * 512]);
  __asm__ volatile("s_waitcnt lgkmcnt(0)" ::: "memory");  // own Tbs ds_writes committed

  int sl = 0, sn = 2;
  #pragma unroll 1
  for (int kt = 0; kt < 16; ++kt) {
    const int k0 = kt * 64;
    const u16* Kc = &Ks[sl][0];
    const u16* Vc = &Vs[kt & 1][0];
    if (kt < 15)
      __asm__ volatile("s_waitcnt vmcnt(1)" ::: "memory");  // V(kt),K(kt) resident; K(kt+1) in flight
    else
      __asm__ volatile("s_waitcnt vmcnt(0)" ::: "memory");  // tail drain
    __builtin_amdgcn_s_barrier();
    __asm__ volatile("" ::: "memory");
    // stage V(kt+1) then K(kt+2): FIFO at next top = [V(kt+1), K(kt+2)] after K(kt+1) lands
    if (kt < 15) async16(Vsrc + (kt + 1) * 64, &Vs[(kt + 1) & 1][w * 512]);
    if (kt < 14) async16(Ksrc + (size_t)((kt + 2) * 64) * 64, &Ks[sn][w * 512]);
    // bias into MFMA C operand from the LDS slice:
    //   Tbs[j] = Th[j + 768 - q0]; needed Th[k - q + 1023] -> j = k0+16mt+4quad+r - c + 255 - 32w - 16nt
    f32x4 sc[4][2];
    const int jb = k0 + quad * 4 - c + 255 - 32 * w;
    #pragma unroll
    for (int mt = 0; mt < 4; ++mt)
      #pragma unroll
      for (int nt = 0; nt < 2; ++nt) {
        const float* tp = Tbs + jb + mt * 16 - nt * 16;
        sc[mt][nt][0] = tp[0]; sc[mt][nt][1] = tp[1]; sc[mt][nt][2] = tp[2]; sc[mt][nt][3] = tp[3];
      }
    // S^T = K.Q^T
    __builtin_amdgcn_s_setprio(1);
    #pragma unroll
    for (int mt = 0; mt < 4; ++mt) {
      const bf16x8 kf0 = *(const bf16x8*)(Kc + (mt * 2 + 0) * 512 + lane * 8);
      const bf16x8 kf1 = *(const bf16x8*)(Kc + (mt * 2 + 1) * 512 + lane * 8);
      #pragma unroll
      for (int nt = 0; nt < 2; ++nt) {
        sc[mt][nt] = __builtin_amdgcn_mfma_f32_16x16x32_bf16(kf0, qf[nt][0], sc[mt][nt], 0, 0, 0);
        sc[mt][nt] = __builtin_amdgcn_mfma_f32_16x16x32_bf16(kf1, qf[nt][1], sc[mt][nt], 0, 0, 0);
      }
    }
    __builtin_amdgcn_s_setprio(0);
    // exp -> rsum partial -> v_perm pack 4 consecutive k as one b64 swizzled LDS write
    #pragma unroll
    for (int mt = 0; mt < 4; ++mt)
      #pragma unroll
      for (int nt = 0; nt < 2; ++nt) {
        const float p0 = __expf(sc[mt][nt][0]), p1 = __expf(sc[mt][nt][1]);
        const float p2 = __expf(sc[mt][nt][2]), p3 = __expf(sc[mt][nt][3]);
        rsum[nt] += (p0 + p1) + (p2 + p3);
        const u32 lo = pkbf(p0, p1), hi = pkbf(p2, p3);
        const u64 pk = (u64)lo | ((u64)hi << 32);
        const int ch = (mt * 2 + (quad >> 1)) ^ (c & 7);
        *(u64*)(PsW + (nt * 16 + c) * 64 + ch * 8 + (quad & 1) * 4) = pk;
      }
    __asm__ volatile("s_waitcnt lgkmcnt(0)" ::: "memory");  // own P writes visible
    // out^T += V^T . P^T
    bf16x8 pf[2][2];
    #pragma unroll
    for (int nt = 0; nt < 2; ++nt)
      #pragma unroll
      for (int kk = 0; kk < 2; ++kk) {
        const int ch = (kk * 4 + quad) ^ (c & 7);
        pf[nt][kk] = *(const bf16x8*)(PsW + (nt * 16 + c) * 64 + ch * 8);
      }
    __builtin_amdgcn_s_setprio(1);
    #pragma unroll
    for (int dt = 0; dt < 4; ++dt) {
      const bf16x8 vf0 = *(const bf16x8*)(Vc + (dt * 2 + 0) * 512 + lane * 8);
      const bf16x8 vf1 = *(const bf16x8*)(Vc + (dt * 2 + 1) * 512 + lane * 8);
      #pragma unroll
      for (int nt = 0; nt < 2; ++nt) {
        oacc[dt][nt] = __builtin_amdgcn_mfma_f32_16x16x32_bf16(vf0, pf[nt][0], oacc[dt][nt], 0, 0, 0);
        oacc[dt][nt] = __builtin_amdgcn_mfma_f32_16x16x32_bf16(vf1, pf[nt][1], oacc[dt][nt], 0, 0, 0);
      }
    }
    __builtin_amdgcn_s_setprio(0);
    sl = (sl == 2) ? 0 : sl + 1;
    sn = (sn == 2) ? 0 : sn + 1;
  }

  // fold quads: lanes (c, c+16, c+32, c+48) hold disjoint k-partitions of q-row c
  #pragma unroll
  for (int nt = 0; nt < 2; ++nt) {
    rsum[nt] += __shfl_xor(rsum[nt], 16);
    rsum[nt] += __shfl_xor(rsum[nt], 32);
  }

  #pragma unroll
  for (int nt = 0; nt < 2; ++nt) {
    const float inv = 1.0f / rsum[nt];
    const int q = qw + nt * 16 + c;
    #pragma unroll
    for (int dt = 0; dt < 4; ++dt) {
      const u64 pk = (u64)f2bf(oacc[dt][nt][0] * inv) | ((u64)f2bf(oacc[dt][nt][1] * inv) << 16) |
                     ((u64)f2bf(oacc[dt][nt][2] * inv) << 32) | ((u64)f2bf(oacc[dt][nt][3] * inv) << 48);
      // ctx layout: [b, s, h, dk]; lane holds 4 consecutive dk = dt*16 + quad*4 + r
      *(u64*)(ctx + (((size_t)b * 1024 + q) * 16 + h) * 64 + dt * 16 + quad * 4) = pk;
    }
  }
}

extern "C" void kernel_launch(void* const* d_in, const int* in_sizes, int n_in,
                              void* d_out, int out_size, void* d_ws, size_t ws_size,
                              hipStream_t stream) {
  const void* hidden = d_in[0];
  const void* lnw = d_in[1];
  const void* wq = d_in[2];
  const void* wk = d_in[3];
  const void* wv = d_in[4];
  const void* wo = d_in[5];
  const void* relb = d_in[6];
  char* ws = (char*)d_ws;

  u16* normed = (u16*)(ws);                        // 16 MB; reused as ctx after QKV
  u16* Qb = (u16*)(ws + ((size_t)16 << 20));       // 16 MB
  u16* Kb = (u16*)(ws + ((size_t)32 << 20));       // 16 MB
  u16* VTb = (u16*)(ws + ((size_t)48 << 20));      // 16 MB
  u16* wtq = (u16*)(ws + ((size_t)64 << 20));      // [3072][1024] fused B: wtq|wtk|wtv
  u16* wtk = (u16*)(ws + ((size_t)64 << 20) + (2 << 20));
  u16* wtv = (u16*)(ws + ((size_t)64 << 20) + (4 << 20));
  u16* wto = (u16*)(ws + ((size_t)64 << 20) + (6 << 20));
  float* Tb = (float*)(ws + ((size_t)64 << 20) + (8 << 20));  // 131 KB
  int* flag = (int*)(ws + ((size_t)64 << 20) + (9 << 20));

  dim3 b256(256);
  detect_kernel<<<dim3(1), b256, 0, stream>>>((const u32*)hidden, flag);
  prep_rms_kernel<<<dim3(16, 16, 37), b256, 0, stream>>>(wq, wk, wv, wo, wtq, wtk, wtv,
                                                         wto, relb, Tb, hidden, lnw,
                                                         normed, flag);
  qkv_gemm32_kernel<<<dim3(768), dim3(512), 0, stream>>>(normed, wtq, Qb, Kb, VTb);
  attn_kernel<<<dim3(512), dim3(512), 0, stream>>>(Qb, Kb, VTb, Tb, normed);
  out_gemm256_kernel<<<dim3(256), dim3(512), 0, stream>>>(normed, wto, hidden, d_out, flag);
}